// Round 1
// baseline (141.891 us; speedup 1.0000x reference)
//
#include <hip/hip_runtime.h>
#include <math.h>

#define NB      100000
#define TRAIN   50000
#define SPIN    365
#define CHUNK_L 49
#define WARM    128
#define TPB     64
#define NCHUNK  ((NB + CHUNK_L - 1) / CHUNK_L)     /* 2041 */
#define NBLK    ((NCHUNK + TPB - 1) / TPB)         /* 32   */
#define STAGE_MAX (TPB * CHUNK_L + WARM)           /* 3264 */

// ---------------- Kernel 1: obs std (ddof=1) + softmax gates -> ws ----------
__global__ void k_reduce_gates(const float* __restrict__ y_obs,
                               const float* __restrict__ w0,
                               const float* __restrict__ w1,
                               const float* __restrict__ w2,
                               float* __restrict__ ws) {
    __shared__ double ssum[256];
    __shared__ double ssq[256];
    int tid = threadIdx.x;
    double s = 0.0, q = 0.0;
    for (int i = SPIN + tid; i < TRAIN; i += 256) {
        double v = (double)y_obs[i];
        s += v;
        q += v * v;
    }
    ssum[tid] = s;
    ssq[tid]  = q;
    __syncthreads();
    for (int off = 128; off > 0; off >>= 1) {
        if (tid < off) {
            ssum[tid] += ssum[tid + off];
            ssq[tid]  += ssq[tid + off];
        }
        __syncthreads();
    }
    if (tid == 0) {
        double n    = (double)(TRAIN - SPIN);
        double mean = ssum[0] / n;
        double var  = (ssq[0] - n * mean * mean) / (n - 1.0);
        float stdv  = (float)sqrt(var);
        float e0 = expf(w0[0]);
        float e1 = expf(w1[0]);
        float e2 = expf(w2[0]);
        float denom = e0 + e1 + e2;
        ws[0] = e0 / denom;   // oo
        ws[1] = e1 / denom;   // ol
        ws[2] = stdv;         // obs std
    }
}

// ---------------- Kernel 2: speculative chunked scan ------------------------
// Contraction: 0 <= dc1/dc0 <= 1-oo <= 0.845 -> 128 warm-up steps give
// residual error <~ 4e-10, far below the 3.4e-2 absmax threshold.
__global__ __launch_bounds__(TPB) void k_scan(const float* __restrict__ x,
                                              const float* __restrict__ ws,
                                              float* __restrict__ out) {
    __shared__ float su1[STAGE_MAX];
    __shared__ float su2[STAGE_MAX];

    const float oo = ws[0];
    const float ol = ws[1];

    int tid     = threadIdx.x;
    int bchunk0 = blockIdx.x * TPB;
    int bstart  = bchunk0 * CHUNK_L;
    int r0      = max(0, bstart - WARM);
    int r1      = min(NB, bstart + TPB * CHUNK_L);
    int cnt     = r1 - r0;

    // Coalesced stage of this block's x window into LDS (SoA, stride 49 words
    // across lanes -> coprime with 32 banks -> conflict-free reads).
    const float2* x2 = (const float2*)x;
    for (int i = tid; i < cnt; i += TPB) {
        float2 v = x2[r0 + i];
        su1[i] = v.x;
        su2[i] = v.y;
    }
    __syncthreads();

    int chunk = bchunk0 + tid;
    if (chunk >= NCHUNK) return;

    int s0     = chunk * CHUNK_L;
    int send   = min(s0 + CHUNK_L, NB);
    int wstart = max(0, s0 - WARM);

    // wstart==0 -> exact start from the true initial state c=0.
    float c    = (wstart == 0) ? 0.0f : 1.0f;
    const float omoo = 1.0f - oo;

    // Warm-up (no outputs)
    for (int t = wstart; t < s0; ++t) {
        float u1 = su1[t - r0];
        float u2 = su2[t - r0];
        float r  = __builtin_amdgcn_rcpf(c);
        float z  = ol - u2 * r;
        float el = (z > 0.0f) ? z : (__expf(z) - 1.0f);
        float praw    = ol - el;
        float olc_raw = (c > 0.0f) ? praw : ol;
        float f  = fmaxf(omoo - olc_raw, 0.0f);
        c = fmaf(f, c, u1);
    }

    float* __restrict__ h_n    = out;
    float* __restrict__ c_n    = out + 1 * NB;
    float* __restrict__ l_n    = out + 2 * NB;
    float* __restrict__ lc_n   = out + 3 * NB;
    float* __restrict__ g_olc  = out + 8 * NB;
    float* __restrict__ g_f    = out + 9 * NB;
    float* __restrict__ h_nout = out + 10 * NB;

    // Output phase: outputs at step t use c BEFORE the state update.
    for (int t = s0; t < send; ++t) {
        float u1 = su1[t - r0];
        float u2 = su2[t - r0];
        float r  = __builtin_amdgcn_rcpf(c);
        float z  = ol - u2 * r;
        float el = (z > 0.0f) ? z : (__expf(z) - 1.0f);
        float praw    = ol - el;
        float olc_raw = (c > 0.0f) ? praw : ol;
        float f   = fmaxf(omoo - olc_raw, 0.0f);
        float olc = fmaxf(olc_raw, 0.0f);
        float h   = oo * c;

        h_n[t]       = h;
        c_n[t]       = c;
        l_n[t]       = ol * c;
        lc_n[t]      = olc * c;
        g_olc[t]     = olc;
        g_f[t]       = f;
        h_nout[2*t]  = h;

        c = fmaf(f, c, u1);
    }
}

// ---------------- Kernel 3: constant outputs --------------------------------
__global__ void k_fill(const float* __restrict__ ws, float* __restrict__ out) {
    int i = blockIdx.x * blockDim.x + threadIdx.x;
    if (i >= NB) return;
    float oo   = ws[0];
    float ol   = ws[1];
    float stdv = ws[2];
    out[4  * NB + i]         = 0.0f;   // bp_n
    out[5  * NB + i]         = 0.0f;   // Gate_ib
    out[6  * NB + i]         = oo;     // Gate_oo
    out[7  * NB + i]         = ol;     // Gate_ol
    out[12 * NB + i]         = stdv;   // obs_std
    out[10 * NB + 2 * i + 1] = stdv;   // h_nout[:,1]
}

extern "C" void kernel_launch(void* const* d_in, const int* in_sizes, int n_in,
                              void* d_out, int out_size, void* d_ws, size_t ws_size,
                              hipStream_t stream) {
    const float* x     = (const float*)d_in[0];
    const float* y_obs = (const float*)d_in[1];
    const float* w0    = (const float*)d_in[2];
    const float* w1    = (const float*)d_in[3];
    const float* w2    = (const float*)d_in[4];
    // d_in[5] = epoch, d_in[6] = time_lag (both 0, unused)
    float* out = (float*)d_out;
    float* ws  = (float*)d_ws;

    k_reduce_gates<<<1, 256, 0, stream>>>(y_obs, w0, w1, w2, ws);
    k_scan<<<NBLK, TPB, 0, stream>>>(x, ws, out);
    k_fill<<<(NB + 255) / 256, 256, 0, stream>>>(ws, out);
}

// Round 2
// 94.271 us; speedup vs baseline: 1.5051x; 1.5051x over previous
//
#include <hip/hip_runtime.h>
#include <math.h>

#define NB      100000
#define TRAIN   50000
#define SPIN    365
#define CHUNK_L 49
#define WARM    128
#define TPB     64
#define NCHUNK  ((NB + CHUNK_L - 1) / CHUNK_L)     /* 2041 */
#define NBLK    ((NCHUNK + TPB - 1) / TPB)         /* 32   */
#define STAGE_MAX (TPB * CHUNK_L + WARM)           /* 3264 */

#define RED_BLOCKS 64
#define RED_TPB    256
/* aligned bulk region [368, 50000): 49632 floats = 12408 float4 (16B-aligned) */
#define V4_BASE  368
#define V4_COUNT 12408

// ws layout: [0]=oo [1]=ol [2]=stdv [4+2b]=partial_sum [5+2b]=partial_sumsq (as double pairs)
// doubles stored starting at 8-byte aligned offset: use ws_d = (double*)(ws+4)

// ---------------- Kernel 1a: multi-block partial reduction + gates ----------
__global__ __launch_bounds__(RED_TPB) void k_partial(const float* __restrict__ y_obs,
                                                     const float* __restrict__ w0,
                                                     const float* __restrict__ w1,
                                                     const float* __restrict__ w2,
                                                     float* __restrict__ ws) {
    __shared__ double ssum[RED_TPB];
    __shared__ double ssq[RED_TPB];
    int tid = threadIdx.x;
    int gid = blockIdx.x * RED_TPB + tid;

    double s = 0.0, q = 0.0;
    const float4* y4 = (const float4*)(y_obs + V4_BASE);
    for (int i = gid; i < V4_COUNT; i += RED_BLOCKS * RED_TPB) {
        float4 v = y4[i];
        s += (double)v.x + (double)v.y + (double)v.z + (double)v.w;
        q += (double)v.x * v.x + (double)v.y * v.y
           + (double)v.z * v.z + (double)v.w * v.w;
    }
    if (blockIdx.x == 0 && tid == 0) {
        // head elements [365,368)
        for (int i = SPIN; i < V4_BASE; ++i) {
            double v = (double)y_obs[i];
            s += v; q += v * v;
        }
        // gates (only need weights)
        float e0 = expf(w0[0]);
        float e1 = expf(w1[0]);
        float e2 = expf(w2[0]);
        float denom = e0 + e1 + e2;
        ws[0] = e0 / denom;   // oo
        ws[1] = e1 / denom;   // ol
    }
    ssum[tid] = s;
    ssq[tid]  = q;
    __syncthreads();
    for (int off = RED_TPB / 2; off > 0; off >>= 1) {
        if (tid < off) {
            ssum[tid] += ssum[tid + off];
            ssq[tid]  += ssq[tid + off];
        }
        __syncthreads();
    }
    if (tid == 0) {
        double* wsd = (double*)(ws + 4);
        wsd[2 * blockIdx.x]     = ssum[0];
        wsd[2 * blockIdx.x + 1] = ssq[0];
    }
}

// ---------------- Kernel 1b: finalize std -----------------------------------
__global__ __launch_bounds__(64) void k_finalize(float* __restrict__ ws) {
    int tid = threadIdx.x;                 // 64 lanes = 1 wave, RED_BLOCKS=64
    const double* wsd = (const double*)(ws + 4);
    double s = wsd[2 * tid];
    double q = wsd[2 * tid + 1];
    for (int off = 32; off > 0; off >>= 1) {
        s += __shfl_down(s, off, 64);
        q += __shfl_down(q, off, 64);
    }
    if (tid == 0) {
        double n    = (double)(TRAIN - SPIN);
        double mean = s / n;
        double var  = (q - n * mean * mean) / (n - 1.0);
        ws[2] = (float)sqrt(var);
    }
}

// ---------------- Kernel 2: speculative chunked scan ------------------------
// Contraction: 0 <= dc1/dc0 <= 1-oo <= 0.845 -> 128 warm-up steps give
// residual error <~ 4e-10, far below the 3.4e-2 absmax threshold.
__global__ __launch_bounds__(TPB) void k_scan(const float* __restrict__ x,
                                              const float* __restrict__ ws,
                                              float* __restrict__ out) {
    __shared__ float su1[STAGE_MAX];
    __shared__ float su2[STAGE_MAX];

    const float oo = ws[0];
    const float ol = ws[1];

    int tid     = threadIdx.x;
    int bchunk0 = blockIdx.x * TPB;
    int bstart  = bchunk0 * CHUNK_L;
    int r0      = max(0, bstart - WARM);
    int r1      = min(NB, bstart + TPB * CHUNK_L);
    int cnt     = r1 - r0;

    // Coalesced stage of this block's x window into LDS (SoA; lane-to-lane
    // stride 49 words is coprime with 32 banks -> conflict-free reads).
    const float2* x2 = (const float2*)x;
    for (int i = tid; i < cnt; i += TPB) {
        float2 v = x2[r0 + i];
        su1[i] = v.x;
        su2[i] = v.y;
    }
    __syncthreads();

    int chunk = bchunk0 + tid;
    if (chunk >= NCHUNK) return;

    int s0     = chunk * CHUNK_L;
    int send   = min(s0 + CHUNK_L, NB);
    int wstart = max(0, s0 - WARM);

    // wstart==0 -> exact start from the true initial state c=0.
    float c    = (wstart == 0) ? 0.0f : 1.0f;
    const float omoo = 1.0f - oo;

    // Warm-up (no outputs)
    for (int t = wstart; t < s0; ++t) {
        float u1 = su1[t - r0];
        float u2 = su2[t - r0];
        float r  = __builtin_amdgcn_rcpf(c);
        float z  = ol - u2 * r;
        float el = (z > 0.0f) ? z : (__expf(z) - 1.0f);
        float praw    = ol - el;
        float olc_raw = (c > 0.0f) ? praw : ol;
        float f  = fmaxf(omoo - olc_raw, 0.0f);
        c = fmaf(f, c, u1);
    }

    float* __restrict__ h_n    = out;
    float* __restrict__ c_n    = out + 1 * NB;
    float* __restrict__ l_n    = out + 2 * NB;
    float* __restrict__ lc_n   = out + 3 * NB;
    float* __restrict__ g_olc  = out + 8 * NB;
    float* __restrict__ g_f    = out + 9 * NB;
    float* __restrict__ h_nout = out + 10 * NB;

    // Output phase: outputs at step t use c BEFORE the state update.
    for (int t = s0; t < send; ++t) {
        float u1 = su1[t - r0];
        float u2 = su2[t - r0];
        float r  = __builtin_amdgcn_rcpf(c);
        float z  = ol - u2 * r;
        float el = (z > 0.0f) ? z : (__expf(z) - 1.0f);
        float praw    = ol - el;
        float olc_raw = (c > 0.0f) ? praw : ol;
        float f   = fmaxf(omoo - olc_raw, 0.0f);
        float olc = fmaxf(olc_raw, 0.0f);
        float h   = oo * c;

        h_n[t]       = h;
        c_n[t]       = c;
        l_n[t]       = ol * c;
        lc_n[t]      = olc * c;
        g_olc[t]     = olc;
        g_f[t]       = f;
        h_nout[2*t]  = h;

        c = fmaf(f, c, u1);
    }
}

// ---------------- Kernel 3: constant outputs --------------------------------
__global__ void k_fill(const float* __restrict__ ws, float* __restrict__ out) {
    int i = blockIdx.x * blockDim.x + threadIdx.x;
    if (i >= NB) return;
    float oo   = ws[0];
    float ol   = ws[1];
    float stdv = ws[2];
    out[4  * NB + i]         = 0.0f;   // bp_n
    out[5  * NB + i]         = 0.0f;   // Gate_ib
    out[6  * NB + i]         = oo;     // Gate_oo
    out[7  * NB + i]         = ol;     // Gate_ol
    out[12 * NB + i]         = stdv;   // obs_std
    out[10 * NB + 2 * i + 1] = stdv;   // h_nout[:,1]
}

extern "C" void kernel_launch(void* const* d_in, const int* in_sizes, int n_in,
                              void* d_out, int out_size, void* d_ws, size_t ws_size,
                              hipStream_t stream) {
    const float* x     = (const float*)d_in[0];
    const float* y_obs = (const float*)d_in[1];
    const float* w0    = (const float*)d_in[2];
    const float* w1    = (const float*)d_in[3];
    const float* w2    = (const float*)d_in[4];
    // d_in[5] = epoch, d_in[6] = time_lag (both 0, unused)
    float* out = (float*)d_out;
    float* ws  = (float*)d_ws;

    k_partial<<<RED_BLOCKS, RED_TPB, 0, stream>>>(y_obs, w0, w1, w2, ws);
    k_finalize<<<1, 64, 0, stream>>>(ws);
    k_scan<<<NBLK, TPB, 0, stream>>>(x, ws, out);
    k_fill<<<(NB + 255) / 256, 256, 0, stream>>>(ws, out);
}